// Round 3
// baseline (22532.425 us; speedup 1.0000x reference)
//
#include <hip/hip_runtime.h>
#include <hip/hip_cooperative_groups.h>
#include <float.h>
#include <math.h>

namespace cg = cooperative_groups;

#define B_  64
#define S_  256
#define E_  300
#define E4_ 75      // E/4
#define H_  512
#define J4_ 128     // H/4
#define T_  10

// ---- workspace layout (f32 element offsets) ----
// x:     [S][E4][B][4]            gathered embeddings, float4-interleaved, batch-coalesced
// hbuf:  [2 parity][2 dir][J4][B][4]   carried hidden state (published)
// houts: [S][2 dir][J4][B][4]     masked hidden outputs (0 where masked)
// feats: [B][S][T]
#define X_OFF     0
#define X_SZ      (S_*E4_*B_*4)
#define HSLAB     (J4_*B_*4)            // 32768 dwords per (parity,dir)
#define HBUF_OFF  (X_OFF + X_SZ)
#define HBUF_SZ   (4*HSLAB)
#define HOUT_OFF  (HBUF_OFF + HBUF_SZ)
#define HOUT_SZ   (S_*2*HSLAB)
#define FEAT_OFF  (HOUT_OFF + HOUT_SZ)
#define FEAT_SZ   (B_*S_*T_)

__global__ __launch_bounds__(256) void k_fused(
    const int* __restrict__ tok, const int* __restrict__ lengths,
    const float* __restrict__ emb,
    const float* __restrict__ wih_f, const float* __restrict__ whh_f, const float* __restrict__ b_f,
    const float* __restrict__ wih_b, const float* __restrict__ whh_b, const float* __restrict__ b_b,
    const float* __restrict__ w_out, const float* __restrict__ b_out,
    const float* __restrict__ start_t, const float* __restrict__ end_t, const float* __restrict__ trans,
    float* __restrict__ ws, int* __restrict__ out)
{
    cg::grid_group grid = cg::this_grid();
    const int bid = blockIdx.x;
    const int tid = threadIdx.x;
    const int gthread = bid * 256 + tid;

    // ---------- phase 0: zero parity-0 h, gather embeddings ----------
    {
        float* z = ws + HBUF_OFF;            // parity 0, both dirs
        for (int i = gthread; i < 2 * HSLAB; i += 65536) z[i] = 0.f;

        float4* xp = reinterpret_cast<float4*>(ws + X_OFF);
        const int total = S_ * E4_ * B_;     // 1,228,800 float4s
        for (int i = gthread; i < total; i += 65536) {
            int b    = i & 63;
            int rest = i >> 6;
            int e4   = rest % E4_;
            int s    = rest / E4_;
            const float4* src = reinterpret_cast<const float4*>(
                emb + (size_t)tok[b * S_ + s] * E_ + e4 * 4);   // emb rows are 16B-aligned (1200B)
            xp[i] = *src;
        }
    }
    __threadfence();
    grid.sync();

    // ---------- phase 1: 256 recurrence steps ----------
    {
        const int d  = bid >> 7;
        const int jb = bid & 127;
        const int w  = tid >> 6;
        const int b  = tid & 63;
        const int j  = __builtin_amdgcn_readfirstlane(jb * 4 + w);  // SGPR -> scalar weight loads
        const int j4 = j >> 2, ju = j & 3;

        const float* wih  = d ? wih_b : wih_f;
        const float* whh  = d ? whh_b : whh_f;
        const float* bias = d ? b_b  : b_f;

        const float* w0 = whh + (size_t)(0 * H_ + j) * H_;
        const float* w1 = whh + (size_t)(1 * H_ + j) * H_;
        const float* w2 = whh + (size_t)(2 * H_ + j) * H_;
        const float* w3 = whh + (size_t)(3 * H_ + j) * H_;
        const float* v0 = wih + (size_t)(0 * H_ + j) * E_;
        const float* v1 = wih + (size_t)(1 * H_ + j) * E_;
        const float* v2 = wih + (size_t)(2 * H_ + j) * E_;
        const float* v3 = wih + (size_t)(3 * H_ + j) * E_;
        const float bi0 = bias[0 * H_ + j], bi1 = bias[1 * H_ + j];
        const float bi2 = bias[2 * H_ + j], bi3 = bias[3 * H_ + j];

        const int len = lengths[b];
        float ccur = 0.f;      // cell state lives in a register (owned by this wave)
        float hcur = 0.f;      // own published h (avoids re-read)

        for (int sIdx = 0; sIdx < S_; sIdx++) {
            const int s = d ? (S_ - 1 - sIdx) : sIdx;
            const int p = sIdx & 1;
            const float4* hp = reinterpret_cast<const float4*>(ws + HBUF_OFF + (size_t)(p * 2 + d) * HSLAB);
            const float4* xp = reinterpret_cast<const float4*>(ws + X_OFF) + (size_t)s * E4_ * B_;

            float a0 = 0.f, a1 = 0.f, a2 = 0.f, a3 = 0.f;
#pragma unroll 8
            for (int k4 = 0; k4 < J4_; k4++) {
                float4 h4 = hp[k4 * B_ + b];
                const float* p0 = w0 + k4 * 4; const float* p1 = w1 + k4 * 4;
                const float* p2 = w2 + k4 * 4; const float* p3 = w3 + k4 * 4;
                a0 += p0[0]*h4.x + p0[1]*h4.y + p0[2]*h4.z + p0[3]*h4.w;
                a1 += p1[0]*h4.x + p1[1]*h4.y + p1[2]*h4.z + p1[3]*h4.w;
                a2 += p2[0]*h4.x + p2[1]*h4.y + p2[2]*h4.z + p2[3]*h4.w;
                a3 += p3[0]*h4.x + p3[1]*h4.y + p3[2]*h4.z + p3[3]*h4.w;
            }
#pragma unroll 5
            for (int e4 = 0; e4 < E4_; e4++) {
                float4 x4 = xp[e4 * B_ + b];
                const float* p0 = v0 + e4 * 4; const float* p1 = v1 + e4 * 4;
                const float* p2 = v2 + e4 * 4; const float* p3 = v3 + e4 * 4;
                a0 += p0[0]*x4.x + p0[1]*x4.y + p0[2]*x4.z + p0[3]*x4.w;
                a1 += p1[0]*x4.x + p1[1]*x4.y + p1[2]*x4.z + p1[3]*x4.w;
                a2 += p2[0]*x4.x + p2[1]*x4.y + p2[2]*x4.z + p2[3]*x4.w;
                a3 += p3[0]*x4.x + p3[1]*x4.y + p3[2]*x4.z + p3[3]*x4.w;
            }

            const float g0 = a0 + bi0, g1 = a1 + bi1, g2 = a2 + bi2, g3 = a3 + bi3;
            const bool  m  = (s < len);
            const float iG = 1.f / (1.f + expf(-g0));
            const float fG = 1.f / (1.f + expf(-g1));
            const float gG = tanhf(g2);
            const float oG = 1.f / (1.f + expf(-g3));
            const float c_new = fG * ccur + iG * gG;
            const float h_new = oG * tanhf(c_new);
            ccur = m ? c_new : ccur;
            const float h_pub = m ? h_new : hcur;
            hcur = h_pub;

            float* hn = ws + HBUF_OFF + (size_t)((p ^ 1) * 2 + d) * HSLAB;
            hn[(j4 * B_ + b) * 4 + ju] = h_pub;
            ws[HOUT_OFF + (size_t)((s * 2 + d) * J4_ + j4) * (B_ * 4) + b * 4 + ju] = m ? h_new : 0.f;

            __threadfence();
            grid.sync();
        }
    }

    // ---------- phase 2: output projection (WG = one s) ----------
    {
        const int s  = bid;
        const int t0 = tid >> 6;
        const int b  = tid & 63;
        const float4* hp = reinterpret_cast<const float4*>(ws + HOUT_OFF) + (size_t)s * 2 * J4_ * B_;
        for (int t = t0; t < T_; t += 4) {
            const int tu = __builtin_amdgcn_readfirstlane(t);
            const float* wr = w_out + (size_t)tu * (2 * H_);
            float acc = b_out[tu];
#pragma unroll 4
            for (int q = 0; q < 2 * J4_; q++) {
                float4 h4 = hp[q * B_ + b];
                const float* wq = wr + q * 4;
                acc += wq[0]*h4.x + wq[1]*h4.y + wq[2]*h4.z + wq[3]*h4.w;
            }
            ws[FEAT_OFF + ((size_t)b * S_ + s) * T_ + tu] = acc;
        }
    }
    __threadfence();
    grid.sync();

    // ---------- phase 3: Viterbi (WGs 0..63, wave 0) ----------
    __shared__ unsigned char bpl[S_][T_];
    if (bid < B_) {
        const int b = bid;
        if (tid < 64) {
            const int lane = tid;
            const int tt = (lane < T_) ? lane : 0;
            const float* fb = ws + FEAT_OFF + (size_t)b * S_ * T_;
            float tr[T_];
#pragma unroll
            for (int i = 0; i < T_; i++) tr[i] = trans[i * T_ + tt];   // column tt
            const int len = lengths[b];
            float score = start_t[tt] + fb[tt];
            for (int s = 1; s < S_; s++) {
                float em = fb[s * T_ + tt];
                float best = -FLT_MAX;
                int bi = 0;
#pragma unroll
                for (int i = 0; i < T_; i++) {
                    float si = __shfl(score, i);
                    float c = si + tr[i];
                    if (c > best) { best = c; bi = i; }   // strict > : first-max like argmax
                }
                bool m = (s < len);
                score = m ? (best + em) : score;
                if (lane < T_) bpl[s][lane] = (unsigned char)(m ? bi : lane);
            }
            float tot = score + end_t[tt];
            float best = -FLT_MAX;
            int last = 0;
#pragma unroll
            for (int i = 0; i < T_; i++) {
                float v = __shfl(tot, i);
                if (v > best) { best = v; last = i; }
            }
            if (lane == 0) bpl[0][0] = (unsigned char)last;  // stash
        }
        __syncthreads();
        if (tid == 0) {
            const int len = lengths[b];
            int tag = bpl[0][0];
            out[b * S_ + (S_ - 1)] = ((S_ - 1) < len) ? tag : 0;
            for (int s = S_ - 2; s >= 0; s--) {
                tag = bpl[s + 1][tag];
                out[b * S_ + s] = (s < len) ? tag : 0;
            }
        }
    }
}

// -------------------- launcher --------------------
extern "C" void kernel_launch(void* const* d_in, const int* in_sizes, int n_in,
                              void* d_out, int out_size, void* d_ws, size_t ws_size,
                              hipStream_t stream) {
    const int*   tok   = (const int*)  d_in[0];
    const int*   len   = (const int*)  d_in[1];
    const float* emb   = (const float*)d_in[2];
    const float* wih_f = (const float*)d_in[3];
    const float* whh_f = (const float*)d_in[4];
    const float* b_f   = (const float*)d_in[5];
    const float* wih_b = (const float*)d_in[6];
    const float* whh_b = (const float*)d_in[7];
    const float* b_b   = (const float*)d_in[8];
    const float* w_out = (const float*)d_in[9];
    const float* b_out = (const float*)d_in[10];
    const float* st    = (const float*)d_in[11];
    const float* en    = (const float*)d_in[12];
    const float* tr    = (const float*)d_in[13];

    float* ws = (float*)d_ws;
    int* out = (int*)d_out;

    void* args[16] = {
        (void*)&tok, (void*)&len, (void*)&emb,
        (void*)&wih_f, (void*)&whh_f, (void*)&b_f,
        (void*)&wih_b, (void*)&whh_b, (void*)&b_b,
        (void*)&w_out, (void*)&b_out,
        (void*)&st, (void*)&en, (void*)&tr,
        (void*)&ws, (void*)&out
    };
    hipLaunchCooperativeKernel(reinterpret_cast<const void*>(&k_fused),
                               dim3(256), dim3(256), args, 0, stream);
}

// Round 4
// 8511.500 us; speedup vs baseline: 2.6473x; 2.6473x over previous
//
#include <hip/hip_runtime.h>
#include <hip/hip_bf16.h>
#include <float.h>
#include <math.h>

#define B_  64
#define S_  256
#define E_  300
#define E4_ 75      // E/4
#define H_  512
#define J4_ 128     // H/4
#define T_  10

// ---- workspace layout (f32 element offsets) ----
// x:     [S][E4][B][4]                 gathered embeddings, float4-interleaved, batch-coalesced
// hbuf:  6 slabs of HSLAB:             slab = p0d0,p0d1, c_d0,c_d1, p1d0,p1d1
//        each slab [J4][B][4]          (hidden/cell state, float4-interleaved)
// houts: [S][2 dir][J4][B][4]          masked hidden outputs (0 where masked)
// feats: [B][S][T]
#define X_OFF     0
#define X_SZ      (S_*E4_*B_*4)
#define HSLAB     (J4_*B_*4)            // 32768 floats per slab
#define HBUF_OFF  (X_OFF + X_SZ)
#define HBUF_SZ   (6*HSLAB)
#define HOUT_OFF  (HBUF_OFF + HBUF_SZ)
#define HOUT_SZ   (S_*2*HSLAB)
#define FEAT_OFF  (HOUT_OFF + HOUT_SZ)
#define FEAT_SZ   (B_*S_*T_)

// -------------------- embedding gather: x[s][e4][b][.] = emb[tok[b][s]][e4*4+.] ----------
__global__ void k_gather(const int* __restrict__ tok, const float* __restrict__ emb,
                         float4* __restrict__ xp) {
    const int total = S_ * E4_ * B_;     // 1,228,800 float4s
    for (int i = blockIdx.x * blockDim.x + threadIdx.x; i < total;
         i += gridDim.x * blockDim.x) {
        int b    = i & 63;
        int rest = i >> 6;
        int e4   = rest % E4_;
        int s    = rest / E4_;
        xp[i] = *reinterpret_cast<const float4*>(
            emb + (size_t)tok[b * S_ + s] * E_ + e4 * 4);   // emb rows are 1200B (16B-aligned)
    }
}

// -------------------- one LSTM time step (both directions) --------------------
// grid 256 = (d:2) x (jb:128); block 1024 = 16 waves = (j_local:4 x kq:4), lane = batch.
// Each wave computes a k-quarter partial of all 4 gates of hidden unit j = jb*4+j_local;
// LDS reduce + 256-thread combine does activations and the state update.
__global__ __launch_bounds__(1024) void k_step(
    const float* __restrict__ wih_f, const float* __restrict__ whh_f, const float* __restrict__ b_f,
    const float* __restrict__ wih_b, const float* __restrict__ whh_b, const float* __restrict__ b_b,
    const int* __restrict__ lengths, float* __restrict__ ws, int sIdx) {

    const int d   = blockIdx.x >> 7;
    const int jb  = blockIdx.x & 127;
    const int tid = threadIdx.x;
    const int w   = tid >> 6;          // wave 0..15
    const int b   = tid & 63;
    const int jl  = w >> 2;            // j_local 0..3
    const int kq  = w & 3;             // k-quarter 0..3
    const int j   = __builtin_amdgcn_readfirstlane(jb * 4 + jl);  // SGPR -> scalar weight loads

    const int s = d ? (S_ - 1 - sIdx) : sIdx;
    const int p = sIdx & 1;

    const float* wih  = d ? wih_b : wih_f;
    const float* whh  = d ? whh_b : whh_f;
    const float* bias = d ? b_b  : b_f;

    const float4* hp = reinterpret_cast<const float4*>(ws + HBUF_OFF + (size_t)(p * 4 + d) * HSLAB);
    const float4* xp = reinterpret_cast<const float4*>(ws + X_OFF) + (size_t)s * E4_ * B_;

    // recurrent weights: rows g*H+j, k-quarter slice
    const float* w0 = whh + (size_t)(0 * H_ + j) * H_ + kq * 128;
    const float* w1 = whh + (size_t)(1 * H_ + j) * H_ + kq * 128;
    const float* w2 = whh + (size_t)(2 * H_ + j) * H_ + kq * 128;
    const float* w3 = whh + (size_t)(3 * H_ + j) * H_ + kq * 128;
    // input weights: 75 float4s split 19/19/19/18
    const int xoff = kq * 19;
    const int xlen = (kq == 3) ? 18 : 19;
    const float* v0 = wih + (size_t)(0 * H_ + j) * E_ + xoff * 4;
    const float* v1 = wih + (size_t)(1 * H_ + j) * E_ + xoff * 4;
    const float* v2 = wih + (size_t)(2 * H_ + j) * E_ + xoff * 4;
    const float* v3 = wih + (size_t)(3 * H_ + j) * E_ + xoff * 4;

    float a0 = 0.f, a1 = 0.f, a2 = 0.f, a3 = 0.f;

#pragma unroll 8
    for (int k4 = 0; k4 < 32; k4++) {
        float4 h4 = hp[(kq * 32 + k4) * B_ + b];
        const float* p0 = w0 + k4 * 4; const float* p1 = w1 + k4 * 4;
        const float* p2 = w2 + k4 * 4; const float* p3 = w3 + k4 * 4;
        a0 += p0[0]*h4.x + p0[1]*h4.y + p0[2]*h4.z + p0[3]*h4.w;
        a1 += p1[0]*h4.x + p1[1]*h4.y + p1[2]*h4.z + p1[3]*h4.w;
        a2 += p2[0]*h4.x + p2[1]*h4.y + p2[2]*h4.z + p2[3]*h4.w;
        a3 += p3[0]*h4.x + p3[1]*h4.y + p3[2]*h4.z + p3[3]*h4.w;
    }
#pragma unroll 4
    for (int e4 = 0; e4 < xlen; e4++) {
        float4 x4 = xp[(xoff + e4) * B_ + b];
        const float* p0 = v0 + e4 * 4; const float* p1 = v1 + e4 * 4;
        const float* p2 = v2 + e4 * 4; const float* p3 = v3 + e4 * 4;
        a0 += p0[0]*x4.x + p0[1]*x4.y + p0[2]*x4.z + p0[3]*x4.w;
        a1 += p1[0]*x4.x + p1[1]*x4.y + p1[2]*x4.z + p1[3]*x4.w;
        a2 += p2[0]*x4.x + p2[1]*x4.y + p2[2]*x4.z + p2[3]*x4.w;
        a3 += p3[0]*x4.x + p3[1]*x4.y + p3[2]*x4.z + p3[3]*x4.w;
    }

    __shared__ float part[16][4][64];      // [wave][gate][b] — lane-stride 1, conflict-free
    part[w][0][b] = a0;
    part[w][1][b] = a1;
    part[w][2][b] = a2;
    part[w][3][b] = a3;
    __syncthreads();

    if (tid < 256) {
        const int jl2 = tid >> 6;          // 0..3
        const int b2  = tid & 63;
        const int j2  = __builtin_amdgcn_readfirstlane(jb * 4 + jl2);

        float g0 = part[jl2*4+0][0][b2] + part[jl2*4+1][0][b2] + part[jl2*4+2][0][b2] + part[jl2*4+3][0][b2];
        float g1 = part[jl2*4+0][1][b2] + part[jl2*4+1][1][b2] + part[jl2*4+2][1][b2] + part[jl2*4+3][1][b2];
        float g2 = part[jl2*4+0][2][b2] + part[jl2*4+1][2][b2] + part[jl2*4+2][2][b2] + part[jl2*4+3][2][b2];
        float g3 = part[jl2*4+0][3][b2] + part[jl2*4+1][3][b2] + part[jl2*4+2][3][b2] + part[jl2*4+3][3][b2];
        g0 += bias[0 * H_ + j2];
        g1 += bias[1 * H_ + j2];
        g2 += bias[2 * H_ + j2];
        g3 += bias[3 * H_ + j2];

        const int  len = lengths[b2];
        const bool m   = (s < len);

        const float iG = 1.f / (1.f + expf(-g0));
        const float fG = 1.f / (1.f + expf(-g1));
        const float gG = tanhf(g2);
        const float oG = 1.f / (1.f + expf(-g3));

        // state addresses: [j4=jb][b][ju=jl2]
        const size_t sidx = (size_t)(jb * B_ + b2) * 4 + jl2;
        float* cp = ws + HBUF_OFF + (size_t)(2 + d) * HSLAB + sidx;
        const float c_old = *cp;
        const float c_new = fG * c_old + iG * gG;
        const float h_new = oG * tanhf(c_new);
        const float h_old = ws[HBUF_OFF + (size_t)(p * 4 + d) * HSLAB + sidx];

        *cp = m ? c_new : c_old;
        ws[HBUF_OFF + (size_t)((p ^ 1) * 4 + d) * HSLAB + sidx] = m ? h_new : h_old;
        ws[HOUT_OFF + ((size_t)(s * 2 + d) * J4_ + jb) * (B_ * 4) + b2 * 4 + jl2] = m ? h_new : 0.f;
    }
}

// -------------------- output projection: feats[b][s][t] --------------------
// grid 256 (per s); block 640 = 10 waves (t) x 64 lanes (b)
__global__ __launch_bounds__(640) void k_feats(const float* __restrict__ w_out,
                                               const float* __restrict__ b_out,
                                               float* __restrict__ ws) {
    const int s = blockIdx.x;
    const int t = __builtin_amdgcn_readfirstlane((int)threadIdx.x >> 6);  // 0..9
    const int b = threadIdx.x & 63;
    const float4* hp = reinterpret_cast<const float4*>(ws + HOUT_OFF) + (size_t)s * 2 * J4_ * B_;
    const float* wr = w_out + (size_t)t * (2 * H_);
    float acc = b_out[t];
#pragma unroll 4
    for (int q = 0; q < 2 * J4_; q++) {
        float4 h4 = hp[q * B_ + b];
        const float* wq = wr + q * 4;   // column d*H + j4*4 + ju matches q = d*J4 + j4
        acc += wq[0]*h4.x + wq[1]*h4.y + wq[2]*h4.z + wq[3]*h4.w;
    }
    ws[FEAT_OFF + ((size_t)b * S_ + s) * T_ + t] = acc;
}

// -------------------- Viterbi decode (one wave per batch row) --------------------
__global__ __launch_bounds__(64) void k_viterbi(const float* __restrict__ start_t,
                                                const float* __restrict__ end_t,
                                                const float* __restrict__ trans,
                                                const int* __restrict__ lengths,
                                                const float* __restrict__ ws,
                                                int* __restrict__ out) {
    const int b = blockIdx.x;
    const int lane = threadIdx.x;
    const int tt = (lane < T_) ? lane : 0;
    const float* feats = ws + FEAT_OFF;
    __shared__ unsigned char bpl[S_][T_];

    float tr[T_];
#pragma unroll
    for (int i = 0; i < T_; i++) tr[i] = trans[i * T_ + tt];   // column tt

    const int len = lengths[b];
    const float* fb = feats + (size_t)b * S_ * T_;
    float score = start_t[tt] + fb[tt];

    for (int s = 1; s < S_; s++) {
        float em = fb[s * T_ + tt];
        float best = -FLT_MAX;
        int bi = 0;
#pragma unroll
        for (int i = 0; i < T_; i++) {
            float si = __shfl(score, i);
            float c = si + tr[i];
            if (c > best) { best = c; bi = i; }   // strict > : first-max like argmax
        }
        bool m = (s < len);
        score = m ? (best + em) : score;
        if (lane < T_) bpl[s][lane] = (unsigned char)(m ? bi : lane);
    }

    float tot = score + end_t[tt];
    float best = -FLT_MAX;
    int last = 0;
#pragma unroll
    for (int i = 0; i < T_; i++) {
        float v = __shfl(tot, i);
        if (v > best) { best = v; last = i; }
    }
    __syncthreads();
    if (lane == 0) {
        int tag = last;
        out[b * S_ + (S_ - 1)] = ((S_ - 1) < len) ? tag : 0;
        for (int s = S_ - 2; s >= 0; s--) {
            tag = bpl[s + 1][tag];
            out[b * S_ + s] = (s < len) ? tag : 0;
        }
    }
}

// -------------------- launcher --------------------
extern "C" void kernel_launch(void* const* d_in, const int* in_sizes, int n_in,
                              void* d_out, int out_size, void* d_ws, size_t ws_size,
                              hipStream_t stream) {
    const int*   tok   = (const int*)  d_in[0];
    const int*   len   = (const int*)  d_in[1];
    const float* emb   = (const float*)d_in[2];
    const float* wih_f = (const float*)d_in[3];
    const float* whh_f = (const float*)d_in[4];
    const float* b_f   = (const float*)d_in[5];
    const float* wih_b = (const float*)d_in[6];
    const float* whh_b = (const float*)d_in[7];
    const float* b_b   = (const float*)d_in[8];
    const float* w_out = (const float*)d_in[9];
    const float* b_out = (const float*)d_in[10];
    const float* st    = (const float*)d_in[11];
    const float* en    = (const float*)d_in[12];
    const float* tr    = (const float*)d_in[13];

    float* ws = (float*)d_ws;
    int* out = (int*)d_out;

    // zero parity-0 hidden slabs + both cell slabs (slabs 0..3); parity-1 written before read
    hipMemsetAsync(ws + HBUF_OFF, 0, (size_t)4 * HSLAB * sizeof(float), stream);

    k_gather<<<1024, 256, 0, stream>>>(tok, emb, reinterpret_cast<float4*>(ws + X_OFF));

    for (int sIdx = 0; sIdx < S_; sIdx++) {
        k_step<<<256, 1024, 0, stream>>>(wih_f, whh_f, b_f, wih_b, whh_b, b_b, len, ws, sIdx);
    }

    k_feats<<<256, 640, 0, stream>>>(w_out, b_out, ws);
    k_viterbi<<<64, 64, 0, stream>>>(st, en, tr, len, ws, out);
}

// Round 5
// 4221.326 us; speedup vs baseline: 5.3378x; 2.0163x over previous
//
#include <hip/hip_runtime.h>
#include <hip/hip_bf16.h>
#include <float.h>
#include <math.h>

#define B_  64
#define S_  256
#define E_  300
#define E4_ 75      // E/4
#define H_  512
#define J4_ 128     // H/4
#define T_  10

// ---- workspace layout (f32 element offsets) ----
// x:     [S][E4][B][4]                 gathered embeddings, float4-interleaved, batch-coalesced
// hbuf:  6 slabs of HSLAB:             slab = p0d0,p0d1, c_d0,c_d1, p1d0,p1d1
//        each slab [J4][B][4]          (hidden/cell state, float4-interleaved)
// houts: [S][2 dir][J4][B][4]          masked hidden outputs (0 where masked)
// feats: [B][S][T]
#define X_OFF     0
#define X_SZ      (S_*E4_*B_*4)
#define HSLAB     (J4_*B_*4)            // 32768 floats per slab
#define HBUF_OFF  (X_OFF + X_SZ)
#define HBUF_SZ   (6*HSLAB)
#define HOUT_OFF  (HBUF_OFF + HBUF_SZ)
#define HOUT_SZ   (S_*2*HSLAB)
#define FEAT_OFF  (HOUT_OFF + HOUT_SZ)
#define FEAT_SZ   (B_*S_*T_)

// -------------------- embedding gather: x[s][e4][b][.] = emb[tok[b][s]][e4*4+.] ----------
__global__ void k_gather(const int* __restrict__ tok, const float* __restrict__ emb,
                         float4* __restrict__ xp) {
    const int total = S_ * E4_ * B_;     // 1,228,800 float4s
    for (int i = blockIdx.x * blockDim.x + threadIdx.x; i < total;
         i += gridDim.x * blockDim.x) {
        int b    = i & 63;
        int rest = i >> 6;
        int e4   = rest % E4_;
        int s    = rest / E4_;
        xp[i] = *reinterpret_cast<const float4*>(
            emb + (size_t)tok[b * S_ + s] * E_ + e4 * 4);   // emb rows are 1200B (16B-aligned)
    }
}

// -------------------- one LSTM time step (both directions) --------------------
// grid 256 = (d:2) x (jb:128); block 512 = 8 waves = (gate g:4 x k-half kh:2), lane = batch.
// Weights staged to LDS via coalesced float4 vector loads (NO scalar s_load path),
// then read back as wave-uniform ds_read_b128 broadcasts (conflict-free).
__global__ __launch_bounds__(512) void k_step(
    const float* __restrict__ wih_f, const float* __restrict__ whh_f, const float* __restrict__ b_f,
    const float* __restrict__ wih_b, const float* __restrict__ whh_b, const float* __restrict__ b_b,
    const int* __restrict__ lengths, float* __restrict__ ws, int sIdx) {

    const int d   = blockIdx.x >> 7;
    const int jb  = blockIdx.x & 127;
    const int tid = threadIdx.x;

    const float* wih  = d ? wih_b : wih_f;
    const float* whh  = d ? whh_b : whh_f;
    const float* bias = d ? b_b  : b_f;

    __shared__ float4 wrec[16][128];    // [row = g*4+j][k4]  : 32 KB
    __shared__ float4 wx  [16][76];     // [row = g*4+j][e4]  : 19456 B (75 used)
    __shared__ float  part[8][4][64];   // [wave = g*2+kh][j][b] : 8 KB

    // ---- stage weights into LDS (coalesced float4 vector loads) ----
    for (int c = tid; c < 16 * 128; c += 512) {        // recurrent: 16 rows x 128 float4
        int row = c >> 7;                              // g*4 + j
        int k4  = c & 127;
        int g = row >> 2, j = row & 3;
        wrec[row][k4] = *reinterpret_cast<const float4*>(
            whh + ((size_t)g * H_ + jb * 4 + j) * H_ + k4 * 4);
    }
    for (int c = tid; c < 16 * 75; c += 512) {         // input: 16 rows x 75 float4
        int row = c / 75;
        int e4  = c - row * 75;
        int g = row >> 2, j = row & 3;
        wx[row][e4] = *reinterpret_cast<const float4*>(
            wih + ((size_t)g * H_ + jb * 4 + j) * E_ + e4 * 4);
    }
    __syncthreads();

    // ---- compute partial gate pre-activations ----
    const int w  = tid >> 6;         // wave 0..7
    const int b  = tid & 63;
    const int g  = w >> 1;           // gate 0..3
    const int kh = w & 1;            // k-half

    const int s = d ? (S_ - 1 - sIdx) : sIdx;
    const int p = sIdx & 1;

    const float4* hp = reinterpret_cast<const float4*>(ws + HBUF_OFF + (size_t)(p * 4 + d) * HSLAB);
    const float4* xp = reinterpret_cast<const float4*>(ws + X_OFF) + (size_t)s * E4_ * B_;

    float a0 = 0.f, a1 = 0.f, a2 = 0.f, a3 = 0.f;

    const int kbeg = kh * 64, kend = kh * 64 + 64;
#pragma unroll 4
    for (int k4 = kbeg; k4 < kend; k4++) {
        float4 h4 = hp[k4 * B_ + b];
        float4 q0 = wrec[g * 4 + 0][k4];
        float4 q1 = wrec[g * 4 + 1][k4];
        float4 q2 = wrec[g * 4 + 2][k4];
        float4 q3 = wrec[g * 4 + 3][k4];
        a0 += q0.x*h4.x + q0.y*h4.y + q0.z*h4.z + q0.w*h4.w;
        a1 += q1.x*h4.x + q1.y*h4.y + q1.z*h4.z + q1.w*h4.w;
        a2 += q2.x*h4.x + q2.y*h4.y + q2.z*h4.z + q2.w*h4.w;
        a3 += q3.x*h4.x + q3.y*h4.y + q3.z*h4.z + q3.w*h4.w;
    }
    const int ebeg = kh ? 38 : 0, eend = kh ? 75 : 38;
#pragma unroll 4
    for (int e4 = ebeg; e4 < eend; e4++) {
        float4 x4 = xp[e4 * B_ + b];
        float4 q0 = wx[g * 4 + 0][e4];
        float4 q1 = wx[g * 4 + 1][e4];
        float4 q2 = wx[g * 4 + 2][e4];
        float4 q3 = wx[g * 4 + 3][e4];
        a0 += q0.x*x4.x + q0.y*x4.y + q0.z*x4.z + q0.w*x4.w;
        a1 += q1.x*x4.x + q1.y*x4.y + q1.z*x4.z + q1.w*x4.w;
        a2 += q2.x*x4.x + q2.y*x4.y + q2.z*x4.z + q2.w*x4.w;
        a3 += q3.x*x4.x + q3.y*x4.y + q3.z*x4.z + q3.w*x4.w;
    }

    part[w][0][b] = a0;
    part[w][1][b] = a1;
    part[w][2][b] = a2;
    part[w][3][b] = a3;
    __syncthreads();

    // ---- combine: activations + state update (threads 0..255 = (j_local:4 x b:64)) ----
    if (tid < 256) {
        const int jl = tid >> 6;
        const int b2 = tid & 63;

        float gv[4];
#pragma unroll
        for (int g2 = 0; g2 < 4; g2++)
            gv[g2] = part[g2 * 2 + 0][jl][b2] + part[g2 * 2 + 1][jl][b2]
                   + bias[g2 * H_ + jb * 4 + jl];

        const int  len = lengths[b2];
        const bool m   = (s < len);

        const float iG = 1.f / (1.f + expf(-gv[0]));
        const float fG = 1.f / (1.f + expf(-gv[1]));
        const float gG = tanhf(gv[2]);
        const float oG = 1.f / (1.f + expf(-gv[3]));

        const size_t sidx = (size_t)(jb * B_ + b2) * 4 + jl;
        float* cp = ws + HBUF_OFF + (size_t)(2 + d) * HSLAB + sidx;
        const float c_old = *cp;
        const float c_new = fG * c_old + iG * gG;
        const float h_new = oG * tanhf(c_new);
        const float h_old = ws[HBUF_OFF + (size_t)(p * 4 + d) * HSLAB + sidx];

        *cp = m ? c_new : c_old;
        ws[HBUF_OFF + (size_t)((p ^ 1) * 4 + d) * HSLAB + sidx] = m ? h_new : h_old;
        ws[HOUT_OFF + ((size_t)(s * 2 + d) * J4_ + jb) * (B_ * 4) + b2 * 4 + jl] = m ? h_new : 0.f;
    }
}

// -------------------- output projection: feats[b][s][t] --------------------
// grid 256 (per s); block 640 = 10 waves (t) x 64 lanes (b)
__global__ __launch_bounds__(640) void k_feats(const float* __restrict__ w_out,
                                               const float* __restrict__ b_out,
                                               float* __restrict__ ws) {
    const int s = blockIdx.x;
    const int t = __builtin_amdgcn_readfirstlane((int)threadIdx.x >> 6);  // 0..9
    const int b = threadIdx.x & 63;
    const float4* hp = reinterpret_cast<const float4*>(ws + HOUT_OFF) + (size_t)s * 2 * J4_ * B_;
    const float* wr = w_out + (size_t)t * (2 * H_);
    float acc = b_out[t];
#pragma unroll 4
    for (int q = 0; q < 2 * J4_; q++) {
        float4 h4 = hp[q * B_ + b];
        const float* wq = wr + q * 4;   // column d*H + j4*4 + ju matches q = d*J4 + j4
        acc += wq[0]*h4.x + wq[1]*h4.y + wq[2]*h4.z + wq[3]*h4.w;
    }
    ws[FEAT_OFF + ((size_t)b * S_ + s) * T_ + t] = acc;
}

// -------------------- Viterbi decode (one wave per batch row) --------------------
__global__ __launch_bounds__(64) void k_viterbi(const float* __restrict__ start_t,
                                                const float* __restrict__ end_t,
                                                const float* __restrict__ trans,
                                                const int* __restrict__ lengths,
                                                const float* __restrict__ ws,
                                                int* __restrict__ out) {
    const int b = blockIdx.x;
    const int lane = threadIdx.x;
    const int tt = (lane < T_) ? lane : 0;
    const float* feats = ws + FEAT_OFF;
    __shared__ unsigned char bpl[S_][T_];

    float tr[T_];
#pragma unroll
    for (int i = 0; i < T_; i++) tr[i] = trans[i * T_ + tt];   // column tt

    const int len = lengths[b];
    const float* fb = feats + (size_t)b * S_ * T_;
    float score = start_t[tt] + fb[tt];

    for (int s = 1; s < S_; s++) {
        float em = fb[s * T_ + tt];
        float best = -FLT_MAX;
        int bi = 0;
#pragma unroll
        for (int i = 0; i < T_; i++) {
            float si = __shfl(score, i);
            float c = si + tr[i];
            if (c > best) { best = c; bi = i; }   // strict > : first-max like argmax
        }
        bool m = (s < len);
        score = m ? (best + em) : score;
        if (lane < T_) bpl[s][lane] = (unsigned char)(m ? bi : lane);
    }

    float tot = score + end_t[tt];
    float best = -FLT_MAX;
    int last = 0;
#pragma unroll
    for (int i = 0; i < T_; i++) {
        float v = __shfl(tot, i);
        if (v > best) { best = v; last = i; }
    }
    __syncthreads();
    if (lane == 0) {
        int tag = last;
        out[b * S_ + (S_ - 1)] = ((S_ - 1) < len) ? tag : 0;
        for (int s = S_ - 2; s >= 0; s--) {
            tag = bpl[s + 1][tag];
            out[b * S_ + s] = (s < len) ? tag : 0;
        }
    }
}

// -------------------- launcher --------------------
extern "C" void kernel_launch(void* const* d_in, const int* in_sizes, int n_in,
                              void* d_out, int out_size, void* d_ws, size_t ws_size,
                              hipStream_t stream) {
    const int*   tok   = (const int*)  d_in[0];
    const int*   len   = (const int*)  d_in[1];
    const float* emb   = (const float*)d_in[2];
    const float* wih_f = (const float*)d_in[3];
    const float* whh_f = (const float*)d_in[4];
    const float* b_f   = (const float*)d_in[5];
    const float* wih_b = (const float*)d_in[6];
    const float* whh_b = (const float*)d_in[7];
    const float* b_b   = (const float*)d_in[8];
    const float* w_out = (const float*)d_in[9];
    const float* b_out = (const float*)d_in[10];
    const float* st    = (const float*)d_in[11];
    const float* en    = (const float*)d_in[12];
    const float* tr    = (const float*)d_in[13];

    float* ws = (float*)d_ws;
    int* out = (int*)d_out;

    // zero parity-0 hidden slabs + both cell slabs (slabs 0..3); parity-1 written before read
    hipMemsetAsync(ws + HBUF_OFF, 0, (size_t)4 * HSLAB * sizeof(float), stream);

    k_gather<<<1024, 256, 0, stream>>>(tok, emb, reinterpret_cast<float4*>(ws + X_OFF));

    for (int sIdx = 0; sIdx < S_; sIdx++) {
        k_step<<<256, 512, 0, stream>>>(wih_f, whh_f, b_f, wih_b, whh_b, b_b, len, ws, sIdx);
    }

    k_feats<<<256, 640, 0, stream>>>(w_out, b_out, ws);
    k_viterbi<<<64, 64, 0, stream>>>(st, en, tr, len, ws, out);
}